// Round 1
// baseline (979.793 us; speedup 1.0000x reference)
//
#include <hip/hip_runtime.h>
#include <stdint.h>

#define S 2048
#define D 64
#define NH 32              // B*H = 2*16
#define KTILE 32
#define QTILE 64           // q rows per block: 2 subtiles x 32
#define NKT (S / 2 / KTILE)  // 32 tiles per key-half wave

typedef short bf16x8 __attribute__((ext_vector_type(8)));
typedef float f32x4  __attribute__((ext_vector_type(4)));
typedef float f32x16 __attribute__((ext_vector_type(16)));
typedef int   i32x4  __attribute__((ext_vector_type(4)));

__device__ __forceinline__ short f2bf(float f) {
    // round-to-nearest-even fp32 -> bf16 (bit pattern in a short)
    unsigned u = __float_as_uint(f);
    u = (u + 0x7FFFu + ((u >> 16) & 1u)) >> 16;
    return (short)u;
}

// ---------------- prologue 1: K fp32 -> bf16 row-major ----------------
__global__ __launch_bounds__(256) void cvt_k_kernel(const float* __restrict__ Kg,
                                                    short* __restrict__ Kbf) {
    const size_t t = (size_t)blockIdx.x * 256 + threadIdx.x;
    const float* src = Kg + t * 8;
    f32x4 a = *(const f32x4*)src;
    f32x4 b = *(const f32x4*)(src + 4);
    bf16x8 o;
    #pragma unroll
    for (int j = 0; j < 4; ++j) { o[j] = f2bf(a[j]); o[4 + j] = f2bf(b[j]); }
    *(bf16x8*)(Kbf + t * 8) = o;
}

// ---------------- prologue 2: V fp32 [key][d] -> bf16 V^T [d][key] ----------------
__global__ __launch_bounds__(256) void cvt_vt_kernel(const float* __restrict__ Vg,
                                                     short* __restrict__ Vt) {
    __shared__ short tile[64][72];
    const int h  = blockIdx.x >> 5;
    const int k0 = (blockIdx.x & 31) * 64;
    const int t  = threadIdx.x;
    {
        const int row = t >> 2, dc = (t & 3) * 16;
        const float* src = Vg + ((size_t)h * S + k0 + row) * D + dc;
        bf16x8 a, b;
        #pragma unroll
        for (int j = 0; j < 8; ++j) { a[j] = f2bf(src[j]); b[j] = f2bf(src[8 + j]); }
        *(bf16x8*)&tile[row][dc] = a;
        *(bf16x8*)&tile[row][dc + 8] = b;
    }
    __syncthreads();
    {
        const int d = t >> 2, kc = (t & 3) * 16;
        bf16x8 o0, o1;
        #pragma unroll
        for (int j = 0; j < 8; ++j) { o0[j] = tile[kc + j][d]; o1[j] = tile[kc + 8 + j][d]; }
        short* dst = Vt + ((size_t)h * D + d) * S + k0 + kc;
        *(bf16x8*)dst = o0;
        *(bf16x8*)(dst + 8) = o1;
    }
}

// K A-fragments for one 32-key tile: A[m=key][k=d], m=lane&31, k=hi*8+j (+16*kb)
template<bool PRE>
__device__ __forceinline__ void load_kfrags(const short* __restrict__ Kbf,
                                            const float* __restrict__ Kg,
                                            int h, int key0, int c, int hi,
                                            bf16x8 kf[4]) {
    if constexpr (PRE) {
        const short* kp = Kbf + ((size_t)h * S + key0 + c) * D + hi * 8;
        #pragma unroll
        for (int kb = 0; kb < 4; ++kb) kf[kb] = *(const bf16x8*)(kp + kb * 16);
    } else {
        const float* kp = Kg + ((size_t)h * S + key0 + c) * D + hi * 8;
        #pragma unroll
        for (int kb = 0; kb < 4; ++kb) {
            f32x4 a = *(const f32x4*)(kp + kb * 16);
            f32x4 b = *(const f32x4*)(kp + kb * 16 + 4);
            #pragma unroll
            for (int j = 0; j < 4; ++j) { kf[kb][j] = f2bf(a[j]); kf[kb][4 + j] = f2bf(b[j]); }
        }
    }
}

// Block = 4 waves: wave = qs*2 + kh. qs picks 32 q-rows, kh picks a 1024-key half.
// Swapped score MFMA (A=K, B=Q): lane owns q = lane&31; keys live in regs:
// key(reg) = 8*(reg>>2) + 4*hi + (reg&3). No LDS / no barriers in the k-loops.
template<bool PRE>
__global__ __launch_bounds__(256, 4) void sdpa_kernel(
    const float* __restrict__ Qg, const float* __restrict__ Kg,
    const float* __restrict__ Vg, const short* __restrict__ Kbf,
    const short* __restrict__ Vtbf, float* __restrict__ out_ctx,
    float* __restrict__ out_attn)
{
    __shared__ float sm_stat[2][4][32];   // [m|l][wave][q]   (1 KB)
    __shared__ float sm_ctx[2][32][64];   // [qs][row][d]     (16 KB)

    const int tid  = threadIdx.x;
    const int wave = tid >> 6;
    const int lane = tid & 63;
    const int c    = lane & 31;
    const int hi   = lane >> 5;
    const int qs   = wave >> 1;
    const int kh   = wave & 1;

    // XCD-chunked swizzle: 1024 blocks, 8 XCDs -> 128 contiguous blocks per XCD
    int bid = (int)blockIdx.x;
    bid = (bid & 7) * 128 + (bid >> 3);
    const int h  = bid >> 5;
    const int qb = bid & 31;

    const int q = qb * QTILE + qs * 32 + c;   // this lane's query row

    // Q B-fragments (registers, both passes), pre-scaled by 1/sqrt(64)
    bf16x8 qf[4];
    {
        const float* qrow = Qg + ((size_t)h * S + q) * D + hi * 8;
        #pragma unroll
        for (int kb = 0; kb < 4; ++kb) {
            f32x4 a = *(const f32x4*)(qrow + kb * 16);
            f32x4 b = *(const f32x4*)(qrow + kb * 16 + 4);
            #pragma unroll
            for (int j = 0; j < 4; ++j) {
                qf[kb][j]     = f2bf(a[j] * 0.125f);
                qf[kb][4 + j] = f2bf(b[j] * 0.125f);
            }
        }
    }

    const int kbase = kh * (S / 2);

    // =================== pass A: online row-max + sum-exp ===================
    float m_r = -1e30f, l_r = 0.0f;
    #pragma unroll 1
    for (int kt = 0; kt < NKT; ++kt) {
        const int key0 = kbase + kt * KTILE;
        bf16x8 kf[4];
        load_kfrags<PRE>(Kbf, Kg, h, key0, c, hi, kf);

        f32x16 sacc;
        #pragma unroll
        for (int i = 0; i < 16; ++i) sacc[i] = 0.0f;
        #pragma unroll
        for (int kb = 0; kb < 4; ++kb)
            sacc = __builtin_amdgcn_mfma_f32_32x32x16_bf16(kf[kb], qf[kb], sacc, 0, 0, 0);

        // lane-local max over this tile's 16 keys
        float mx[8];
        #pragma unroll
        for (int i = 0; i < 8; ++i) mx[i] = fmaxf(sacc[i], sacc[i + 8]);
        #pragma unroll
        for (int i = 0; i < 4; ++i) mx[i] = fmaxf(mx[i], mx[i + 4]);
        const float mloc = fmaxf(fmaxf(mx[0], mx[1]), fmaxf(mx[2], mx[3]));
        const float mnew = fmaxf(m_r, mloc);
        float e[16];
        #pragma unroll
        for (int i = 0; i < 16; ++i) e[i] = __expf(sacc[i] - mnew);
        #pragma unroll
        for (int st = 8; st >= 1; st >>= 1)
            #pragma unroll
            for (int i = 0; i < st; ++i) e[i] += e[i + st];
        l_r = l_r * __expf(m_r - mnew) + e[0];
        m_r = mnew;
    }
    // combine key-interleave halves (lane ^ 32 holds the complementary keys)
    {
        const float mo = __shfl_xor(m_r, 32);
        const float lo = __shfl_xor(l_r, 32);
        const float M  = fmaxf(m_r, mo);
        l_r = l_r * __expf(m_r - M) + lo * __expf(mo - M);
        m_r = M;
    }
    // combine across the two key-half waves
    if (hi == 0) { sm_stat[0][wave][c] = m_r; sm_stat[1][wave][c] = l_r; }
    __syncthreads();
    float c_r;   // m + ln(l): p = exp(s - c_r)
    {
        const int pw = wave ^ 1;
        const float mo = sm_stat[0][pw][c];
        const float lo = sm_stat[1][pw][c];
        const float M  = fmaxf(m_r, mo);
        const float L  = l_r * __expf(m_r - M) + lo * __expf(mo - M);
        c_r = M + __logf(L);
    }

    // =================== pass B: emit attn + P.V ===================
    f32x16 cacc[2];
    #pragma unroll
    for (int db = 0; db < 2; ++db)
        #pragma unroll
        for (int i = 0; i < 16; ++i) cacc[db][i] = 0.0f;

    float* arow = out_attn + (size_t)h * S * S + (size_t)q * S + hi * 4;

    #pragma unroll 1
    for (int kt = 0; kt < NKT; ++kt) {
        const int key0 = kbase + kt * KTILE;
        bf16x8 kf[4];
        load_kfrags<PRE>(Kbf, Kg, h, key0, c, hi, kf);

        // V B-fragments: B[k=key][n=d], n=lane&31 (+32*db), k=hi*8+j (+16*ks)
        bf16x8 vf[2][2];
        if constexpr (PRE) {
            #pragma unroll
            for (int db = 0; db < 2; ++db) {
                const short* vp = Vtbf + ((size_t)h * D + db * 32 + c) * S + key0 + hi * 8;
                vf[0][db] = *(const bf16x8*)vp;
                vf[1][db] = *(const bf16x8*)(vp + 16);
            }
        } else {
            #pragma unroll
            for (int ks = 0; ks < 2; ++ks)
                #pragma unroll
                for (int db = 0; db < 2; ++db) {
                    bf16x8 o;
                    #pragma unroll
                    for (int j = 0; j < 8; ++j)
                        o[j] = f2bf(Vg[((size_t)h * S + key0 + ks * 16 + hi * 8 + j) * D + db * 32 + c]);
                    vf[ks][db] = o;
                }
        }

        f32x16 sacc;
        #pragma unroll
        for (int i = 0; i < 16; ++i) sacc[i] = 0.0f;
        #pragma unroll
        for (int kb = 0; kb < 4; ++kb)
            sacc = __builtin_amdgcn_mfma_f32_32x32x16_bf16(kf[kb], qf[kb], sacc, 0, 0, 0);

        // normalized probabilities in-place
        #pragma unroll
        for (int i = 0; i < 16; ++i) sacc[i] = __expf(sacc[i] - c_r);

        // attn: reg groups 4g..4g+3 are keys key0 + 8g + 4*hi + {0..3} -> float4 stores
        #pragma unroll
        for (int g = 0; g < 4; ++g) {
            f32x4 pv = { sacc[4 * g], sacc[4 * g + 1], sacc[4 * g + 2], sacc[4 * g + 3] };
            __builtin_nontemporal_store(pv, (f32x4*)(arow + key0 + 8 * g));
        }

        // pack P to bf16 pairs; build PV A-fragments in-register via permlane32_swap.
        // Frag[ks] needs: dw0,dw1 = half0's group (2ks+hi); dw2,dw3 = half1's same group.
        unsigned P0[4], P1[4];
        #pragma unroll
        for (int g = 0; g < 4; ++g) {
            asm("v_cvt_pk_bf16_f32 %0, %1, %2" : "=v"(P0[g]) : "v"(sacc[4 * g]),     "v"(sacc[4 * g + 1]));
            asm("v_cvt_pk_bf16_f32 %0, %1, %2" : "=v"(P1[g]) : "v"(sacc[4 * g + 2]), "v"(sacc[4 * g + 3]));
        }
        #pragma unroll
        for (int ks = 0; ks < 2; ++ks) {
            unsigned a0 = P0[2 * ks], b0 = P0[2 * ks + 1];
            unsigned a1 = P1[2 * ks], b1 = P1[2 * ks + 1];
            // D.hi <-> S.lo swap: a' = group(2ks+hi) of half0, b' = group(2ks+hi) of half1
            asm("v_permlane32_swap_b32 %0, %1" : "+v"(a0), "+v"(b0));
            asm("v_permlane32_swap_b32 %0, %1" : "+v"(a1), "+v"(b1));
            union { i32x4 w; bf16x8 f; } u;
            i32x4 w = { (int)a0, (int)a1, (int)b0, (int)b1 };
            u.w = w;
            cacc[0] = __builtin_amdgcn_mfma_f32_32x32x16_bf16(u.f, vf[ks][0], cacc[0], 0, 0, 0);
            cacc[1] = __builtin_amdgcn_mfma_f32_32x32x16_bf16(u.f, vf[ks][1], cacc[1], 0, 0, 0);
        }
    }

    // ---- combine ctx across key-half waves, store [B,H,S,D] ----
    if (kh == 1) {
        #pragma unroll
        for (int db = 0; db < 2; ++db)
            #pragma unroll
            for (int i = 0; i < 16; ++i) {
                const int row = (i & 3) + 8 * (i >> 2) + 4 * hi;
                sm_ctx[qs][row][db * 32 + c] = cacc[db][i];
            }
    }
    __syncthreads();
    if (kh == 0) {
        float* crow = out_ctx + ((size_t)h * S + qb * QTILE + qs * 32) * D + c;
        #pragma unroll
        for (int db = 0; db < 2; ++db)
            #pragma unroll
            for (int i = 0; i < 16; ++i) {
                const int row = (i & 3) + 8 * (i >> 2) + 4 * hi;
                __builtin_nontemporal_store(cacc[db][i] + sm_ctx[qs][row][db * 32 + c],
                                            crow + (size_t)row * D + db * 32);
            }
    }
}

extern "C" void kernel_launch(void* const* d_in, const int* in_sizes, int n_in,
                              void* d_out, int out_size, void* d_ws, size_t ws_size,
                              hipStream_t stream) {
    const float* Q = (const float*)d_in[0];
    const float* K = (const float*)d_in[1];
    const float* V = (const float*)d_in[2];
    float* ctx  = (float*)d_out;
    float* attn = (float*)d_out + (size_t)NH * S * D;  // context first, then attn

    const size_t nelem = (size_t)NH * S * D;           // 4,194,304
    const size_t need  = nelem * 2 * sizeof(short);    // 16.8 MB: K_bf + Vt_bf
    short* kbf  = (short*)d_ws;
    short* vtbf = kbf + nelem;

    if (d_ws != nullptr && ws_size >= need) {
        hipLaunchKernelGGL(cvt_k_kernel,  dim3((unsigned)(nelem / 8 / 256)), dim3(256), 0, stream, K, kbf);
        hipLaunchKernelGGL(cvt_vt_kernel, dim3(NH * (S / 64)), dim3(256), 0, stream, V, vtbf);
        hipLaunchKernelGGL(sdpa_kernel<true>,  dim3(1024), dim3(256), 0, stream,
                           Q, K, V, kbf, vtbf, ctx, attn);
    } else {
        // workspace too small: same kernel, fp32 loads + in-loop conversion
        hipLaunchKernelGGL(sdpa_kernel<false>, dim3(1024), dim3(256), 0, stream,
                           Q, K, V, kbf, vtbf, ctx, attn);
    }
}

// Round 2
// 676.506 us; speedup vs baseline: 1.4483x; 1.4483x over previous
//
#include <hip/hip_runtime.h>
#include <stdint.h>

#define S 2048
#define D 64
#define NH 32              // B*H = 2*16
#define KTILE 32
#define QTILE 64           // q rows per block: 2 subtiles x 32
#define NKT (S / 2 / KTILE)  // 32 tiles per key-half wave

typedef short bf16x8 __attribute__((ext_vector_type(8)));
typedef float f32x4  __attribute__((ext_vector_type(4)));
typedef float f32x16 __attribute__((ext_vector_type(16)));
typedef int   i32x4  __attribute__((ext_vector_type(4)));

#define TSTR 36   // transpose-tile row stride in floats: 144B keeps b128 alignment, bank-rot 4

__device__ __forceinline__ short f2bf(float f) {
    // round-to-nearest-even fp32 -> bf16 (bit pattern in a short)
    unsigned u = __float_as_uint(f);
    u = (u + 0x7FFFu + ((u >> 16) & 1u)) >> 16;
    return (short)u;
}

// ---------------- fused prologue: K -> bf16 row-major, V -> bf16 V^T [d][key] ----------------
__global__ __launch_bounds__(256) void cvt_kernel(const float* __restrict__ Kg,
                                                  const float* __restrict__ Vg,
                                                  short* __restrict__ Kbf,
                                                  short* __restrict__ Vt) {
    __shared__ short tile[64][72];
    const int t = threadIdx.x;
    if (blockIdx.x < 2048) {
        const size_t i = (size_t)blockIdx.x * 256 + t;
        const float* src = Kg + i * 8;
        f32x4 a = *(const f32x4*)src;
        f32x4 b = *(const f32x4*)(src + 4);
        bf16x8 o;
        #pragma unroll
        for (int j = 0; j < 4; ++j) { o[j] = f2bf(a[j]); o[4 + j] = f2bf(b[j]); }
        *(bf16x8*)(Kbf + i * 8) = o;
    } else {
        const int bid = (int)blockIdx.x - 2048;
        const int h  = bid >> 5;
        const int k0 = (bid & 31) * 64;
        {
            const int row = t >> 2, dc = (t & 3) * 16;
            const float* src = Vg + ((size_t)h * S + k0 + row) * D + dc;
            bf16x8 a, b;
            #pragma unroll
            for (int j = 0; j < 8; ++j) { a[j] = f2bf(src[j]); b[j] = f2bf(src[8 + j]); }
            *(bf16x8*)&tile[row][dc] = a;
            *(bf16x8*)&tile[row][dc + 8] = b;
        }
        __syncthreads();
        {
            const int d = t >> 2, kc = (t & 3) * 16;
            bf16x8 o0, o1;
            #pragma unroll
            for (int j = 0; j < 8; ++j) { o0[j] = tile[kc + j][d]; o1[j] = tile[kc + 8 + j][d]; }
            short* dst = Vt + ((size_t)h * D + d) * S + k0 + kc;
            *(bf16x8*)dst = o0;
            *(bf16x8*)(dst + 8) = o1;
        }
    }
}

// K A-fragments for one 32-key tile: A[m=key][k=d], m=lane&31, k=hi*8+j (+16*kb)
template<bool PRE>
__device__ __forceinline__ void load_kfrags(const short* __restrict__ Kbf,
                                            const float* __restrict__ Kg,
                                            int h, int key0, int c, int hi,
                                            bf16x8 kf[4]) {
    if constexpr (PRE) {
        const short* kp = Kbf + ((size_t)h * S + key0 + c) * D + hi * 8;
        #pragma unroll
        for (int kb = 0; kb < 4; ++kb) kf[kb] = *(const bf16x8*)(kp + kb * 16);
    } else {
        const float* kp = Kg + ((size_t)h * S + key0 + c) * D + hi * 8;
        #pragma unroll
        for (int kb = 0; kb < 4; ++kb) {
            f32x4 a = *(const f32x4*)(kp + kb * 16);
            f32x4 b = *(const f32x4*)(kp + kb * 16 + 4);
            #pragma unroll
            for (int j = 0; j < 4; ++j) { kf[kb][j] = f2bf(a[j]); kf[kb][4 + j] = f2bf(b[j]); }
        }
    }
}

// Block = 4 waves: wave = qs*2 + kh. qs picks 32 q-rows, kh picks a 1024-key half.
// Swapped score MFMA (A=K, B=Q): lane owns q = lane&31; keys live in regs:
// key(reg) = 8*(reg>>2) + 4*hi + (reg&3). No barriers in the k-loops.
// attn is emitted via a per-wave 32x32 LDS transpose so global stores are full-line dense.
template<bool PRE>
__global__ __launch_bounds__(256, 4) void sdpa_kernel(
    const float* __restrict__ Qg, const float* __restrict__ Kg,
    const float* __restrict__ Vg, const short* __restrict__ Kbf,
    const short* __restrict__ Vtbf, float* __restrict__ out_ctx,
    float* __restrict__ out_attn)
{
    __shared__ float smem[4 * 32 * TSTR];   // per-wave 32xTSTR transpose tiles; reused for ctx combine
    __shared__ float sm_stat[2][4][32];     // [m|l][wave][q]

    const int tid  = threadIdx.x;
    const int wave = tid >> 6;
    const int lane = tid & 63;
    const int c    = lane & 31;
    const int hi   = lane >> 5;
    const int qs   = wave >> 1;
    const int kh   = wave & 1;

    // XCD-chunked swizzle: 1024 blocks, 8 XCDs -> 128 contiguous blocks per XCD
    int bid = (int)blockIdx.x;
    bid = (bid & 7) * 128 + (bid >> 3);
    const int h  = bid >> 5;
    const int qb = bid & 31;

    const int q = qb * QTILE + qs * 32 + c;   // this lane's query row

    // Q B-fragments (registers, both passes), pre-scaled by 1/sqrt(64)
    bf16x8 qf[4];
    {
        const float* qrow = Qg + ((size_t)h * S + q) * D + hi * 8;
        #pragma unroll
        for (int kb = 0; kb < 4; ++kb) {
            f32x4 a = *(const f32x4*)(qrow + kb * 16);
            f32x4 b = *(const f32x4*)(qrow + kb * 16 + 4);
            #pragma unroll
            for (int j = 0; j < 4; ++j) {
                qf[kb][j]     = f2bf(a[j] * 0.125f);
                qf[kb][4 + j] = f2bf(b[j] * 0.125f);
            }
        }
    }

    const int kbase = kh * (S / 2);

    // =================== pass A: online row-max + sum-exp ===================
    float m_r = -1e30f, l_r = 0.0f;
    {
        bf16x8 kf[4];
        load_kfrags<PRE>(Kbf, Kg, h, kbase, c, hi, kf);
        #pragma unroll 1
        for (int kt = 0; kt < NKT; ++kt) {
            // prefetch next K tile (clamped redundant load on the last iter)
            bf16x8 kfn[4];
            const int ktn = (kt + 1 < NKT) ? kt + 1 : kt;
            load_kfrags<PRE>(Kbf, Kg, h, kbase + ktn * KTILE, c, hi, kfn);

            f32x16 sacc;
            #pragma unroll
            for (int i = 0; i < 16; ++i) sacc[i] = 0.0f;
            #pragma unroll
            for (int kb = 0; kb < 4; ++kb)
                sacc = __builtin_amdgcn_mfma_f32_32x32x16_bf16(kf[kb], qf[kb], sacc, 0, 0, 0);

            float mx[8];
            #pragma unroll
            for (int i = 0; i < 8; ++i) mx[i] = fmaxf(sacc[i], sacc[i + 8]);
            #pragma unroll
            for (int i = 0; i < 4; ++i) mx[i] = fmaxf(mx[i], mx[i + 4]);
            const float mloc = fmaxf(fmaxf(mx[0], mx[1]), fmaxf(mx[2], mx[3]));
            const float mnew = fmaxf(m_r, mloc);
            float e[16];
            #pragma unroll
            for (int i = 0; i < 16; ++i) e[i] = __expf(sacc[i] - mnew);
            #pragma unroll
            for (int st = 8; st >= 1; st >>= 1)
                #pragma unroll
                for (int i = 0; i < st; ++i) e[i] += e[i + st];
            l_r = l_r * __expf(m_r - mnew) + e[0];
            m_r = mnew;

            #pragma unroll
            for (int kb = 0; kb < 4; ++kb) kf[kb] = kfn[kb];
        }
    }
    // combine key-interleave halves (lane ^ 32 holds the complementary keys)
    {
        const float mo = __shfl_xor(m_r, 32);
        const float lo = __shfl_xor(l_r, 32);
        const float M  = fmaxf(m_r, mo);
        l_r = l_r * __expf(m_r - M) + lo * __expf(mo - M);
        m_r = M;
    }
    // combine across the two key-half waves
    if (hi == 0) { sm_stat[0][wave][c] = m_r; sm_stat[1][wave][c] = l_r; }
    __syncthreads();
    float c_r;   // m + ln(l): p = exp(s - c_r)
    {
        const int pw = wave ^ 1;
        const float mo = sm_stat[0][pw][c];
        const float lo = sm_stat[1][pw][c];
        const float M  = fmaxf(m_r, mo);
        const float L  = l_r * __expf(m_r - M) + lo * __expf(mo - M);
        c_r = M + __logf(L);
    }

    // =================== pass B: emit attn + P.V ===================
    f32x16 cacc[2];
    #pragma unroll
    for (int db = 0; db < 2; ++db)
        #pragma unroll
        for (int i = 0; i < 16; ++i) cacc[db][i] = 0.0f;

    float* tw = smem + wave * 32 * TSTR;
    float* abase = out_attn + (size_t)h * S * S + (size_t)(qb * QTILE + qs * 32) * S;
    const int tr = lane >> 3;        // row sub-index for dense stores
    const int tc = (lane & 7) * 4;   // key sub-offset (floats)

    bf16x8 kf[4];
    load_kfrags<PRE>(Kbf, Kg, h, kbase, c, hi, kf);

    #pragma unroll 1
    for (int kt = 0; kt < NKT; ++kt) {
        const int key0 = kbase + kt * KTILE;

        // V fragments for this tile (issued early; consumed only after the score MFMAs)
        // B[k=key][n=d]: n=lane&31 (+32*db), k=hi*8+j (+16*ks)
        bf16x8 vf[2][2];
        if constexpr (PRE) {
            #pragma unroll
            for (int db = 0; db < 2; ++db) {
                const short* vp = Vtbf + ((size_t)h * D + db * 32 + c) * S + key0 + hi * 8;
                vf[0][db] = *(const bf16x8*)vp;
                vf[1][db] = *(const bf16x8*)(vp + 16);
            }
        } else {
            #pragma unroll
            for (int ks = 0; ks < 2; ++ks)
                #pragma unroll
                for (int db = 0; db < 2; ++db) {
                    bf16x8 o;
                    #pragma unroll
                    for (int j = 0; j < 8; ++j)
                        o[j] = f2bf(Vg[((size_t)h * S + key0 + ks * 16 + hi * 8 + j) * D + db * 32 + c]);
                    vf[ks][db] = o;
                }
        }

        // prefetch next K tile
        bf16x8 kfn[4];
        const int ktn = (kt + 1 < NKT) ? kt + 1 : kt;
        load_kfrags<PRE>(Kbf, Kg, h, kbase + ktn * KTILE, c, hi, kfn);

        f32x16 sacc;
        #pragma unroll
        for (int i = 0; i < 16; ++i) sacc[i] = 0.0f;
        #pragma unroll
        for (int kb = 0; kb < 4; ++kb)
            sacc = __builtin_amdgcn_mfma_f32_32x32x16_bf16(kf[kb], qf[kb], sacc, 0, 0, 0);

        // normalized probabilities in-place
        #pragma unroll
        for (int i = 0; i < 16; ++i) sacc[i] = __expf(sacc[i] - c_r);

        // --- transpose P through the per-wave LDS tile (reg groups 4g..4g+3 = keys 8g+4hi+{0..3}) ---
        #pragma unroll
        for (int g = 0; g < 4; ++g) {
            f32x4 pv = { sacc[4 * g], sacc[4 * g + 1], sacc[4 * g + 2], sacc[4 * g + 3] };
            *(f32x4*)&tw[c * TSTR + 8 * g + 4 * hi] = pv;
        }

        // pack P to bf16 pairs; build PV A-fragments in-register via permlane32_swap.
        unsigned P0[4], P1[4];
        #pragma unroll
        for (int g = 0; g < 4; ++g) {
            asm("v_cvt_pk_bf16_f32 %0, %1, %2" : "=v"(P0[g]) : "v"(sacc[4 * g]),     "v"(sacc[4 * g + 1]));
            asm("v_cvt_pk_bf16_f32 %0, %1, %2" : "=v"(P1[g]) : "v"(sacc[4 * g + 2]), "v"(sacc[4 * g + 3]));
        }
        #pragma unroll
        for (int ks = 0; ks < 2; ++ks) {
            unsigned a0 = P0[2 * ks], b0 = P0[2 * ks + 1];
            unsigned a1 = P1[2 * ks], b1 = P1[2 * ks + 1];
            asm("v_permlane32_swap_b32 %0, %1" : "+v"(a0), "+v"(b0));
            asm("v_permlane32_swap_b32 %0, %1" : "+v"(a1), "+v"(b1));
            union { i32x4 w; bf16x8 f; } u;
            i32x4 w = { (int)a0, (int)a1, (int)b0, (int)b1 };
            u.w = w;
            cacc[0] = __builtin_amdgcn_mfma_f32_32x32x16_bf16(u.f, vf[ks][0], cacc[0], 0, 0, 0);
            cacc[1] = __builtin_amdgcn_mfma_f32_32x32x16_bf16(u.f, vf[ks][1], cacc[1], 0, 0, 0);
        }

        // --- dense attn stores: each instr writes 8 rows x 128B contiguous (16 full 64B lines) ---
        // same-wave DS RAW: the DS unit processes this wave's LDS ops in order (compiler adds lgkmcnt)
        #pragma unroll
        for (int t = 0; t < 4; ++t) {
            const int row = 8 * t + tr;
            f32x4 p = *(const f32x4*)&tw[row * TSTR + tc];
            __builtin_nontemporal_store(p, (f32x4*)(abase + (size_t)row * S + key0 + tc));
        }

        #pragma unroll
        for (int kb = 0; kb < 4; ++kb) kf[kb] = kfn[kb];
    }

    // ---- combine ctx across key-half waves, store [B,H,S,D] ----
    __syncthreads();   // all waves done with their transpose tiles before smem is reused
    if (kh == 1) {
        #pragma unroll
        for (int db = 0; db < 2; ++db)
            #pragma unroll
            for (int i = 0; i < 16; ++i) {
                const int row = (i & 3) + 8 * (i >> 2) + 4 * hi;
                smem[qs * 2048 + row * 64 + db * 32 + c] = cacc[db][i];
            }
    }
    __syncthreads();
    if (kh == 0) {
        float* crow = out_ctx + ((size_t)h * S + qb * QTILE + qs * 32) * D + c;
        #pragma unroll
        for (int db = 0; db < 2; ++db)
            #pragma unroll
            for (int i = 0; i < 16; ++i) {
                const int row = (i & 3) + 8 * (i >> 2) + 4 * hi;
                __builtin_nontemporal_store(cacc[db][i] + smem[qs * 2048 + row * 64 + db * 32 + c],
                                            crow + (size_t)row * D + db * 32);
            }
    }
}

extern "C" void kernel_launch(void* const* d_in, const int* in_sizes, int n_in,
                              void* d_out, int out_size, void* d_ws, size_t ws_size,
                              hipStream_t stream) {
    const float* Q = (const float*)d_in[0];
    const float* K = (const float*)d_in[1];
    const float* V = (const float*)d_in[2];
    float* ctx  = (float*)d_out;
    float* attn = (float*)d_out + (size_t)NH * S * D;  // context first, then attn

    const size_t nelem = (size_t)NH * S * D;           // 4,194,304
    const size_t need  = nelem * 2 * sizeof(short);    // 16.8 MB: K_bf + Vt_bf
    short* kbf  = (short*)d_ws;
    short* vtbf = kbf + nelem;

    if (d_ws != nullptr && ws_size >= need) {
        hipLaunchKernelGGL(cvt_kernel, dim3(2048 + NH * (S / 64)), dim3(256), 0, stream,
                           K, V, kbf, vtbf);
        hipLaunchKernelGGL(sdpa_kernel<true>,  dim3(1024), dim3(256), 0, stream,
                           Q, K, V, kbf, vtbf, ctx, attn);
    } else {
        // workspace too small: same kernel, fp32 loads + in-loop conversion
        hipLaunchKernelGGL(sdpa_kernel<false>, dim3(1024), dim3(256), 0, stream,
                           Q, K, V, kbf, vtbf, ctx, attn);
    }
}